// Round 1
// baseline (2004.836 us; speedup 1.0000x reference)
//
#include <hip/hip_runtime.h>
#include <hip/hip_bf16.h>

#define N_LAYERS 50
#define N_RES 32
#define N_SKIP 512
#define N_FEAT 8
#define BATCH 8
#define T_IN 8192
#define OUT_LEN 3077
#define NCOL (BATCH * OUT_LEN)   // 24616

// ---------------- workspace layout (bytes) ----------------
#define OFF_HA   ((size_t)0)
#define SZ_H     ((size_t)BATCH * 32 * T_IN * 4)            // 8,388,608
#define OFF_HB   (OFF_HA + SZ_H)
#define OFF_AP   (OFF_HB + SZ_H)                            // packed W_skip [512][1600] f32
#define SZ_AP    ((size_t)512 * 1600 * 4)
#define OFF_BS   (OFF_AP + SZ_AP)                           // bsum[512]
#define SZ_BS    ((size_t)2048)
#define OFF_S    (OFF_BS + SZ_BS)                           // S [512][24616] f32
#define SZ_S     ((size_t)512 * NCOL * 4)
#define OFF_G    (OFF_S + SZ_S)                             // G [1600][24616] bf16
#define SZ_G     ((size_t)1600 * NCOL * 2)
#define OFF_Y1   OFF_G                                      // y1 aliases G (G dead after skip GEMM)

__device__ __forceinline__ float eluf(float v) {
    return v > 0.0f ? v : (__expf(v) - 1.0f);
}

// ---------------- input 1x1 conv: h0[b][o][t] ----------------
__global__ __launch_bounds__(256) void in_conv_kernel(
    const float* __restrict__ x, const float* __restrict__ w_in,
    const float* __restrict__ b_in, float* __restrict__ h0)
{
    int t = blockIdx.x * 256 + threadIdx.x;   // 0..8191 exact
    int b = blockIdx.y;
    const float* xp = x + ((size_t)b * T_IN + t) * N_FEAT;
    float xv[8];
    float4 v0 = *(const float4*)(xp);
    float4 v1 = *(const float4*)(xp + 4);
    xv[0]=v0.x; xv[1]=v0.y; xv[2]=v0.z; xv[3]=v0.w;
    xv[4]=v1.x; xv[5]=v1.y; xv[6]=v1.z; xv[7]=v1.w;
#pragma unroll
    for (int o = 0; o < 32; ++o) {
        float acc = b_in[o];
#pragma unroll
        for (int f = 0; f < 8; ++f) acc += w_in[o * 8 + f] * xv[f];
        h0[((size_t)b * 32 + o) * T_IN + t] = acc;
    }
}

// ---------------- pack W_skip -> A[m][k], k=i*32+c ; bsum ----------------
__global__ __launch_bounds__(256) void pack_skip_kernel(
    const float* __restrict__ w_skip, const float* __restrict__ b_skip,
    float* __restrict__ Apack, float* __restrict__ bsum)
{
    int tid = blockIdx.x * 256 + threadIdx.x;    // 0 .. 819199
    int m = tid / 1600;
    int r = tid - m * 1600;
    int i = r >> 5, c = r & 31;
    Apack[tid] = w_skip[((size_t)i * 512 + m) * 32 + c];
    if (tid < 512) {
        float s = 0.0f;
        for (int l = 0; l < N_LAYERS; ++l) s += b_skip[l * 512 + tid];
        bsum[tid] = s;
    }
}

// ---------------- one dilated gated-conv layer ----------------
// block: 256 thr = 64 columns x 4 channel-quarters
__global__ __launch_bounds__(256) void layer_kernel(
    const float* __restrict__ h_in, float* __restrict__ h_out,
    __hip_bfloat16* __restrict__ G,
    const float* __restrict__ w_sig, const float* __restrict__ b_sig,
    const float* __restrict__ w_tanh, const float* __restrict__ b_tanh,
    const float* __restrict__ w_res, const float* __restrict__ b_res,
    int layer, int d, int Lin, int Lout, int win_start)
{
    __shared__ float gs[64 * 33];
    int tid = threadIdx.x;
    int cl = tid & 63;                 // column-in-block
    int q  = __builtin_amdgcn_readfirstlane(tid >> 6);  // wave-uniform quarter
    int b  = blockIdx.y;
    int t  = blockIdx.x * 64 + cl;
    bool valid = t < Lout;
    int tc = valid ? t : (Lout - 1);

    const float* hb = h_in + (size_t)b * 32 * Lin + tc;
    float x0[32], x1[32];
#pragma unroll
    for (int ci = 0; ci < 32; ++ci) {
        x0[ci] = hb[ci * Lin];
        x1[ci] = hb[ci * Lin + d];
    }

    const float2* ws2 = (const float2*)w_sig  + (size_t)layer * 1024;
    const float2* wt2 = (const float2*)w_tanh + (size_t)layer * 1024;
    float g[8];
#pragma unroll
    for (int j = 0; j < 8; ++j) {
        int c = q * 8 + j;
        float ps = b_sig[layer * 32 + c];
        float pt = b_tanh[layer * 32 + c];
        const float2* wsr = ws2 + c * 32;
        const float2* wtr = wt2 + c * 32;
#pragma unroll
        for (int ci = 0; ci < 32; ++ci) {
            float2 a  = wsr[ci];
            float2 bb = wtr[ci];
            ps += a.x  * x0[ci] + a.y  * x1[ci];
            pt += bb.x * x0[ci] + bb.y * x1[ci];
        }
        float sg = 1.0f / (1.0f + __expf(-ps));
        float e2 = __expf(2.0f * pt);
        float th = 1.0f - 2.0f / (e2 + 1.0f);
        g[j] = sg * th;
        gs[cl * 33 + c] = g[j];
    }

    // write g window rows of G [k][n] (bf16), coalesced along n
    if (valid && t >= win_start) {
        size_t n = (size_t)b * OUT_LEN + (t - win_start);
#pragma unroll
        for (int j = 0; j < 8; ++j) {
            int c = q * 8 + j;
            G[(size_t)(layer * 32 + c) * NCOL + n] = __float2bfloat16(g[j]);
        }
    }

    __syncthreads();
    float gv[32];
#pragma unroll
    for (int ci = 0; ci < 32; ++ci) gv[ci] = gs[cl * 33 + ci];

    const float* wr = w_res + (size_t)layer * 1024;
    if (valid) {
#pragma unroll
        for (int j = 0; j < 8; ++j) {
            int c = q * 8 + j;
            float acc = b_res[layer * 32 + c];
            const float* wrr = wr + c * 32;
#pragma unroll
            for (int ci = 0; ci < 32; ++ci) acc += wrr[ci] * gv[ci];
            float hp = hb[c * Lin + d];   // h_in[b][c][t+d]
            h_out[((size_t)b * 32 + c) * Lout + t] = acc + hp;
        }
    }
}

// ---------------- generic tiled GEMM: C[m][n] = sum_k A[m][k]*f(B[k][n]) + bias[m]
// B_KIND: 1 = bf16 B, no act ; 2 = f32 B with elu-on-load
// BM=BN=128, BK=8, 256 threads, 8x8 per thread (quad layout)
template <int B_KIND>
__global__ __launch_bounds__(256) void gemm_kernel(
    const float* __restrict__ A, const void* __restrict__ Bp,
    float* __restrict__ C, const float* __restrict__ bias,
    int M, int N, int K)
{
    __shared__ float As[8][128];
    __shared__ float Bs[8][128];
    int tid = threadIdx.x;
    int m0 = blockIdx.y * 128, n0 = blockIdx.x * 128;
    int tm = (tid & 15) * 4;          // 0..60
    int tn = (tid >> 4) * 4;          // 0..60
    int am = tid >> 1;                // 0..127
    int ak = (tid & 1) * 4;           // 0|4
    int bk = tid >> 5;                // 0..7
    int bn = (tid & 31) * 4;          // 0..124

    float acc[8][8];
#pragma unroll
    for (int r = 0; r < 8; ++r)
#pragma unroll
        for (int c = 0; c < 8; ++c) acc[r][c] = 0.0f;

    for (int k0 = 0; k0 < K; k0 += 8) {
        float4 av = *(const float4*)(A + (size_t)(m0 + am) * K + k0 + ak);
        float4 bv = make_float4(0.f, 0.f, 0.f, 0.f);
        int gn = n0 + bn;
        if (gn < N) {
            if (B_KIND == 1) {
                const unsigned short* bb = (const unsigned short*)Bp + (size_t)(k0 + bk) * N + gn;
                uint2 u = *(const uint2*)bb;
                bv.x = __uint_as_float(u.x << 16);
                bv.y = __uint_as_float(u.x & 0xffff0000u);
                bv.z = __uint_as_float(u.y << 16);
                bv.w = __uint_as_float(u.y & 0xffff0000u);
            } else {
                bv = *(const float4*)((const float*)Bp + (size_t)(k0 + bk) * N + gn);
                if (B_KIND == 2) {
                    bv.x = eluf(bv.x); bv.y = eluf(bv.y);
                    bv.z = eluf(bv.z); bv.w = eluf(bv.w);
                }
            }
        }
        __syncthreads();
        As[ak + 0][am] = av.x;
        As[ak + 1][am] = av.y;
        As[ak + 2][am] = av.z;
        As[ak + 3][am] = av.w;
        *(float4*)&Bs[bk][bn] = bv;
        __syncthreads();
#pragma unroll
        for (int kk = 0; kk < 8; ++kk) {
            float4 a0 = *(const float4*)&As[kk][tm];
            float4 a1 = *(const float4*)&As[kk][tm + 64];
            float4 b0 = *(const float4*)&Bs[kk][tn];
            float4 b1 = *(const float4*)&Bs[kk][tn + 64];
            float ar[8] = {a0.x, a0.y, a0.z, a0.w, a1.x, a1.y, a1.z, a1.w};
            float br[8] = {b0.x, b0.y, b0.z, b0.w, b1.x, b1.y, b1.z, b1.w};
#pragma unroll
            for (int r = 0; r < 8; ++r)
#pragma unroll
                for (int c = 0; c < 8; ++c) acc[r][c] += ar[r] * br[c];
        }
    }

#pragma unroll
    for (int mi = 0; mi < 2; ++mi)
#pragma unroll
        for (int r = 0; r < 4; ++r) {
            int m = m0 + mi * 64 + tm + r;
            float bb = bias[m];
#pragma unroll
            for (int ni = 0; ni < 2; ++ni) {
                int n = n0 + ni * 64 + tn;
                if (n < N) {
                    float4 v;
                    v.x = acc[mi * 4 + r][ni * 4 + 0] + bb;
                    v.y = acc[mi * 4 + r][ni * 4 + 1] + bb;
                    v.z = acc[mi * 4 + r][ni * 4 + 2] + bb;
                    v.w = acc[mi * 4 + r][ni * 4 + 3] + bb;
                    *(float4*)(C + (size_t)m * N + n) = v;
                }
            }
        }
}

// ---------------- post2: out[n] = b2 + sum_k w2[k]*elu(y1[k][n]) ----------------
__global__ __launch_bounds__(256) void post2_kernel(
    const float* __restrict__ y1, const float* __restrict__ w2,
    const float* __restrict__ b2, float* __restrict__ out, int N)
{
    int n = blockIdx.x * 256 + threadIdx.x;
    if (n >= N) return;
    float acc = b2[0];
    for (int k = 0; k < N_SKIP; ++k) {
        float v = y1[(size_t)k * N + n];
        acc += w2[k] * eluf(v);
    }
    out[n] = acc;
}

extern "C" void kernel_launch(void* const* d_in, const int* in_sizes, int n_in,
                              void* d_out, int out_size, void* d_ws, size_t ws_size,
                              hipStream_t stream)
{
    const float* x      = (const float*)d_in[0];
    const float* w_in   = (const float*)d_in[1];
    const float* b_in   = (const float*)d_in[2];
    const float* w_sig  = (const float*)d_in[3];
    const float* b_sig  = (const float*)d_in[4];
    const float* w_tanh = (const float*)d_in[5];
    const float* b_tanh = (const float*)d_in[6];
    const float* w_skip = (const float*)d_in[7];
    const float* b_skip = (const float*)d_in[8];
    const float* w_res  = (const float*)d_in[9];
    const float* b_res  = (const float*)d_in[10];
    const float* w_post1 = (const float*)d_in[11];
    const float* b_post1 = (const float*)d_in[12];
    const float* w_post2 = (const float*)d_in[13];
    const float* b_post2 = (const float*)d_in[14];
    float* out = (float*)d_out;

    char* ws = (char*)d_ws;
    float* hA = (float*)(ws + OFF_HA);
    float* hB = (float*)(ws + OFF_HB);
    float* Apack = (float*)(ws + OFF_AP);
    float* bsum  = (float*)(ws + OFF_BS);
    float* S     = (float*)(ws + OFF_S);
    __hip_bfloat16* G = (__hip_bfloat16*)(ws + OFF_G);
    float* y1    = (float*)(ws + OFF_Y1);

    in_conv_kernel<<<dim3(T_IN / 256, BATCH), 256, 0, stream>>>(x, w_in, b_in, hA);
    pack_skip_kernel<<<dim3(512 * 1600 / 256), 256, 0, stream>>>(w_skip, b_skip, Apack, bsum);

    int L = T_IN;
    float* hin = hA;
    float* hout = hB;
    for (int i = 0; i < N_LAYERS; ++i) {
        int d = 1 << (i % 10);
        int Lout = L - d;
        dim3 grid((Lout + 63) / 64, BATCH);
        layer_kernel<<<grid, 256, 0, stream>>>(hin, hout, G,
            w_sig, b_sig, w_tanh, b_tanh, w_res, b_res,
            i, d, L, Lout, Lout - OUT_LEN);
        float* tmp = hin; hin = hout; hout = tmp;
        L = Lout;
    }

    // skip GEMM: S[512][NCOL] = Apack(512x1600) * G(1600xNCOL, bf16) + bsum
    gemm_kernel<1><<<dim3((NCOL + 127) / 128, 4), 256, 0, stream>>>(
        Apack, (const void*)G, S, bsum, 512, NCOL, 1600);
    // post1: y1[512][NCOL] = W1(512x512) * elu(S) + b_post1
    gemm_kernel<2><<<dim3((NCOL + 127) / 128, 4), 256, 0, stream>>>(
        w_post1, (const void*)S, y1, b_post1, 512, NCOL, 512);
    // post2
    post2_kernel<<<dim3((NCOL + 255) / 256), 256, 0, stream>>>(y1, w_post2, b_post2, out, NCOL);
}

// Round 2
// 1332.447 us; speedup vs baseline: 1.5046x; 1.5046x over previous
//
#include <hip/hip_runtime.h>
#include <hip/hip_bf16.h>

#define N_LAYERS 50
#define N_RES 32
#define N_SKIP 512
#define N_FEAT 8
#define BATCH 8
#define T_IN 8192
#define OUT_LEN 3077
#define NCOL (BATCH * OUT_LEN)   // 24616

typedef __bf16 bf16x8 __attribute__((ext_vector_type(8)));
typedef float  f32x4  __attribute__((ext_vector_type(4)));

// ---------------- workspace layout (bytes, all 256-aligned) ----------------
#define OFF_HA   ((size_t)0)
#define SZ_H     ((size_t)BATCH * 32 * T_IN * 4)            // 8,388,608
#define OFF_HB   (OFF_HA + SZ_H)
#define OFF_AP   (OFF_HB + SZ_H)                            // Apack bf16 [512][1600]
#define SZ_AP    ((size_t)512 * 1600 * 2)
#define OFF_W1P  (OFF_AP + SZ_AP)                           // w1pack bf16 [512][512]
#define SZ_W1P   ((size_t)512 * 512 * 2)
#define OFF_WLP  (OFF_W1P + SZ_W1P)                         // wlpack f32x4 [50][32][32]
#define SZ_WLP   ((size_t)50 * 1024 * 16)
#define OFF_BS   (OFF_WLP + SZ_WLP)                         // bsum[512] f32
#define SZ_BS    ((size_t)2048)
#define OFF_SB   (OFF_BS + SZ_BS)                           // Sb bf16 [NCOL][512]  (elu applied)
#define SZ_SB    ((size_t)NCOL * 512 * 2)
#define OFF_GT   (OFF_SB + SZ_SB)                           // Gt bf16 [NCOL][1600]
#define SZ_GT    ((size_t)NCOL * 1600 * 2)
#define OFF_Y1   OFF_GT                                     // y1e f32 [512][NCOL] aliases Gt

__device__ __forceinline__ float eluf(float v) {
    return v > 0.0f ? v : (__expf(v) - 1.0f);
}
__device__ __forceinline__ unsigned short f2bf_bits(float f) {
    __hip_bfloat16 h = __float2bfloat16(f);
    return *(unsigned short*)&h;
}
__device__ __forceinline__ void gl_lds16(const void* g, void* l) {
    __builtin_amdgcn_global_load_lds(
        (const __attribute__((address_space(1))) void*)g,
        (__attribute__((address_space(3))) void*)l, 16, 0, 0);
}

// ---------------- input 1x1 conv: h0[b][o][t] ----------------
__global__ __launch_bounds__(256) void in_conv_kernel(
    const float* __restrict__ x, const float* __restrict__ w_in,
    const float* __restrict__ b_in, float* __restrict__ h0)
{
    int t = blockIdx.x * 256 + threadIdx.x;
    int b = blockIdx.y;
    const float* xp = x + ((size_t)b * T_IN + t) * N_FEAT;
    float xv[8];
    float4 v0 = *(const float4*)(xp);
    float4 v1 = *(const float4*)(xp + 4);
    xv[0]=v0.x; xv[1]=v0.y; xv[2]=v0.z; xv[3]=v0.w;
    xv[4]=v1.x; xv[5]=v1.y; xv[6]=v1.z; xv[7]=v1.w;
#pragma unroll
    for (int o = 0; o < 32; ++o) {
        float acc = b_in[o];
#pragma unroll
        for (int f = 0; f < 8; ++f) acc += w_in[o * 8 + f] * xv[f];
        h0[((size_t)b * 32 + o) * T_IN + t] = acc;
    }
}

// ---------------- pack weights ----------------
// Apack[m][i*32+c] = bf16(w_skip[i][m][c]) ; w1pack = bf16(w_post1)
// wlpack[l][c][ci] = {ws0, ws1, wt0, wt1} ; bsum[m] = sum_l b_skip[l][m]
__global__ __launch_bounds__(256) void pack_kernel(
    const float* __restrict__ w_skip, const float* __restrict__ b_skip,
    const float* __restrict__ w_post1,
    const float* __restrict__ w_sig, const float* __restrict__ w_tanh,
    __hip_bfloat16* __restrict__ Apack, __hip_bfloat16* __restrict__ w1pack,
    float4* __restrict__ wlp, float* __restrict__ bsum)
{
    int tid = blockIdx.x * 256 + threadIdx.x;    // 0 .. 819199
    {   // Apack
        int m = tid / 1600;
        int r = tid - m * 1600;
        int i = r >> 5, c = r & 31;
        Apack[tid] = __float2bfloat16(w_skip[((size_t)i * 512 + m) * 32 + c]);
    }
    if (tid < 512 * 512) w1pack[tid] = __float2bfloat16(w_post1[tid]);
    if (tid < 50 * 1024) {
        const float2* s2 = (const float2*)w_sig  + tid;
        const float2* t2 = (const float2*)w_tanh + tid;
        float2 s = *s2, t = *t2;
        wlp[tid] = make_float4(s.x, s.y, t.x, t.y);
    }
    if (tid < 512) {
        float s = 0.0f;
        for (int l = 0; l < N_LAYERS; ++l) s += b_skip[l * 512 + tid];
        bsum[tid] = s;
    }
}

// ---------------- one dilated gated-conv layer ----------------
// block: 256 thr = 64 columns x 4 channel-quarters; weights + h tiles staged in LDS
__global__ __launch_bounds__(256) void layer_kernel(
    const float* __restrict__ h_in, float* __restrict__ h_out,
    __hip_bfloat16* __restrict__ Gt,
    const float4* __restrict__ wlp, const float* __restrict__ wrp,
    const float* __restrict__ b_sig, const float* __restrict__ b_tanh,
    const float* __restrict__ b_res,
    int layer, int d, int Lin, int Lout, int win_start)
{
    __shared__ __align__(16) float4 wp[1024];     // 16 KB {ws0,ws1,wt0,wt1}
    __shared__ float wr[1024];                    // 4 KB  w_res[c][ci]
    __shared__ float xs0[32 * 64];                // 8 KB  h[ci][t0+cl]
    __shared__ float xs1[32 * 64];                // 8 KB  h[ci][t0+cl+d]
    __shared__ float gs[64 * 33];                 // 8.25 KB
    int tid = threadIdx.x;
    int cl = tid & 63;
    int q  = tid >> 6;
    int b  = blockIdx.y;
    int t0 = blockIdx.x * 64;

#pragma unroll
    for (int i = 0; i < 4; ++i)
        wp[i * 256 + tid] = wlp[(size_t)layer * 1024 + i * 256 + tid];
    {
        float4 w = *(const float4*)(wrp + (size_t)layer * 1024 + tid * 4);
        wr[tid*4+0]=w.x; wr[tid*4+1]=w.y; wr[tid*4+2]=w.z; wr[tid*4+3]=w.w;
    }
    {
        int row = tid >> 3;            // 0..31
        int c8  = (tid & 7) * 8;       // 0..56
        const float* hb = h_in + ((size_t)b * 32 + row) * Lin;
        int base = t0 + c8;
        if (t0 + 64 <= Lout) {
            *(float4*)(xs0 + row*64 + c8)     = *(const float4*)(hb + base);
            *(float4*)(xs0 + row*64 + c8 + 4) = *(const float4*)(hb + base + 4);
            *(float4*)(xs1 + row*64 + c8)     = *(const float4*)(hb + base + d);
            *(float4*)(xs1 + row*64 + c8 + 4) = *(const float4*)(hb + base + d + 4);
        } else {
            for (int k = 0; k < 8; ++k) {
                int t = base + k; int tc = t < Lout ? t : (Lout - 1);
                xs0[row*64 + c8 + k] = hb[tc];
                xs1[row*64 + c8 + k] = hb[tc + d];
            }
        }
    }
    __syncthreads();

    float x0[32], x1[32];
#pragma unroll
    for (int ci = 0; ci < 32; ++ci) { x0[ci] = xs0[ci*64 + cl]; x1[ci] = xs1[ci*64 + cl]; }

    int t = t0 + cl;
    bool valid = t < Lout;
    float g[8];
#pragma unroll
    for (int j = 0; j < 8; ++j) {
        int c = q * 8 + j;
        float ps = b_sig[layer * 32 + c];
        float pt = b_tanh[layer * 32 + c];
#pragma unroll
        for (int ci = 0; ci < 32; ++ci) {
            float4 w = wp[c * 32 + ci];          // broadcast ds_read_b128
            ps += w.x * x0[ci] + w.y * x1[ci];
            pt += w.z * x0[ci] + w.w * x1[ci];
        }
        float sg = 1.0f / (1.0f + __expf(-ps));
        float e2 = __expf(2.0f * pt);
        g[j] = sg * (1.0f - 2.0f / (e2 + 1.0f));
        gs[cl * 33 + c] = g[j];
    }

    // Gt[n][layer*32 + q*8 .. +8] bf16, one 16B store
    if (valid && t >= win_start) {
        size_t n = (size_t)b * OUT_LEN + (t - win_start);
        unsigned int w0 = f2bf_bits(g[0]) | ((unsigned)f2bf_bits(g[1]) << 16);
        unsigned int w1 = f2bf_bits(g[2]) | ((unsigned)f2bf_bits(g[3]) << 16);
        unsigned int w2 = f2bf_bits(g[4]) | ((unsigned)f2bf_bits(g[5]) << 16);
        unsigned int w3 = f2bf_bits(g[6]) | ((unsigned)f2bf_bits(g[7]) << 16);
        *(uint4*)(Gt + n * 1600 + layer * 32 + q * 8) = make_uint4(w0, w1, w2, w3);
    }

    __syncthreads();
    float gv[32];
#pragma unroll
    for (int ci = 0; ci < 32; ++ci) gv[ci] = gs[cl * 33 + ci];

    if (valid) {
#pragma unroll
        for (int j = 0; j < 8; ++j) {
            int c = q * 8 + j;
            float acc = b_res[layer * 32 + c];
#pragma unroll
            for (int ci = 0; ci < 32; ++ci) acc += wr[c * 32 + ci] * gv[ci];
            h_out[((size_t)b * 32 + c) * Lout + t] = acc + xs1[c * 64 + cl];
        }
    }
}

// ---------------- MFMA GEMM: C[m][n] = sum_k A[m][k]*B[n][k] + bias[m] ----------------
// 128x128 tile, BK=64, 256 thr (4 waves, each 64x64 = 4x4 of 16x16x32 bf16 MFMA).
// XOR-swizzled LDS (chunk ^= row&7) keeps ds_read_b128 frag loads conflict-free
// while staging stays global_load_lds-linear.
// MODE 0: skip  -> Cout = Sb bf16 [n][512], val = bf16(elu(acc+bias[m]))
// MODE 1: post1 -> Cout = y1e f32 [m][NCOL], val = elu(acc+bias[m])
template <int MODE>
__global__ __launch_bounds__(256) void mfma_gemm_kernel(
    const __hip_bfloat16* __restrict__ A, int lda,
    const __hip_bfloat16* __restrict__ B, int ldb,
    const float* __restrict__ bias, void* __restrict__ Cout, int K)
{
    __shared__ __align__(16) char As[128 * 128];   // 128 rows x 64 bf16 (128 B)
    __shared__ __align__(16) char Bs[128 * 128];
    int tid = threadIdx.x;
    int lane = tid & 63, wave = tid >> 6;
    int m0 = blockIdx.y * 128, n0 = blockIdx.x * 128;
    int wm = (wave & 1) * 64, wn = (wave >> 1) * 64;
    int q = lane >> 4, r = lane & 15;

    f32x4 acc[4][4] = {};

    for (int k0 = 0; k0 < K; k0 += 64) {
        __syncthreads();
#pragma unroll
        for (int i = 0; i < 4; ++i) {
            int li = i * 256 + tid;
            int row = li >> 3, ch = li & 7;
            int cs = (ch ^ (row & 7)) * 8;
            gl_lds16(A + (size_t)(m0 + row) * lda + k0 + cs, As + li * 16);
            int gn = n0 + row; if (gn > NCOL - 1) gn = NCOL - 1;
            gl_lds16(B + (size_t)gn * ldb + k0 + cs, Bs + li * 16);
        }
        __syncthreads();
#pragma unroll
        for (int ks = 0; ks < 2; ++ks) {
            bf16x8 af[4], bfr[4];
#pragma unroll
            for (int s = 0; s < 4; ++s) {
                int m = wm + s * 16 + r;
                int cg = ks * 4 + q;
                af[s]  = *(const bf16x8*)(As + m * 128 + ((cg ^ (m & 7)) * 16));
                int n = wn + s * 16 + r;
                bfr[s] = *(const bf16x8*)(Bs + n * 128 + ((cg ^ (n & 7)) * 16));
            }
#pragma unroll
            for (int i = 0; i < 4; ++i)
#pragma unroll
                for (int j = 0; j < 4; ++j)
                    acc[i][j] = __builtin_amdgcn_mfma_f32_16x16x32_bf16(
                        af[i], bfr[j], acc[i][j], 0, 0, 0);
        }
    }

    if (MODE == 0) {
        __hip_bfloat16* Sb = (__hip_bfloat16*)Cout;
#pragma unroll
        for (int j = 0; j < 4; ++j) {
            int n = n0 + wn + j * 16 + r;
            if (n >= NCOL) continue;
#pragma unroll
            for (int i = 0; i < 4; ++i) {
                int mb = m0 + wm + i * 16 + q * 4;
                float4 bs = *(const float4*)(bias + mb);
                ushort4 u;
                u.x = f2bf_bits(eluf(acc[i][j][0] + bs.x));
                u.y = f2bf_bits(eluf(acc[i][j][1] + bs.y));
                u.z = f2bf_bits(eluf(acc[i][j][2] + bs.z));
                u.w = f2bf_bits(eluf(acc[i][j][3] + bs.w));
                *(ushort4*)(Sb + (size_t)n * 512 + mb) = u;
            }
        }
    } else {
        float* y1e = (float*)Cout;
#pragma unroll
        for (int i = 0; i < 4; ++i) {
            int mb = m0 + wm + i * 16 + q * 4;
            float4 bs = *(const float4*)(bias + mb);
#pragma unroll
            for (int rr = 0; rr < 4; ++rr) {
                float bb = (rr == 0) ? bs.x : (rr == 1) ? bs.y : (rr == 2) ? bs.z : bs.w;
#pragma unroll
                for (int j = 0; j < 4; ++j) {
                    int n = n0 + wn + j * 16 + r;
                    if (n < NCOL)
                        y1e[(size_t)(mb + rr) * NCOL + n] = eluf(acc[i][j][rr] + bb);
                }
            }
        }
    }
}

// ---------------- post2: out[n] = b2 + sum_k w2[k]*y1e[k][n] (y1e already elu'd) ----------------
__global__ __launch_bounds__(256) void post2_kernel(
    const float* __restrict__ y1e, const float* __restrict__ w2,
    const float* __restrict__ b2, float* __restrict__ out, int N)
{
    int n = blockIdx.x * 256 + threadIdx.x;
    if (n >= N) return;
    float acc = b2[0];
    for (int k = 0; k < N_SKIP; ++k)
        acc += w2[k] * y1e[(size_t)k * N + n];
    out[n] = acc;
}

extern "C" void kernel_launch(void* const* d_in, const int* in_sizes, int n_in,
                              void* d_out, int out_size, void* d_ws, size_t ws_size,
                              hipStream_t stream)
{
    const float* x      = (const float*)d_in[0];
    const float* w_in   = (const float*)d_in[1];
    const float* b_in   = (const float*)d_in[2];
    const float* w_sig  = (const float*)d_in[3];
    const float* b_sig  = (const float*)d_in[4];
    const float* w_tanh = (const float*)d_in[5];
    const float* b_tanh = (const float*)d_in[6];
    const float* w_skip = (const float*)d_in[7];
    const float* b_skip = (const float*)d_in[8];
    const float* w_res  = (const float*)d_in[9];
    const float* b_res  = (const float*)d_in[10];
    const float* w_post1 = (const float*)d_in[11];
    const float* b_post1 = (const float*)d_in[12];
    const float* w_post2 = (const float*)d_in[13];
    const float* b_post2 = (const float*)d_in[14];
    float* out = (float*)d_out;

    char* ws = (char*)d_ws;
    float* hA = (float*)(ws + OFF_HA);
    float* hB = (float*)(ws + OFF_HB);
    __hip_bfloat16* Apack  = (__hip_bfloat16*)(ws + OFF_AP);
    __hip_bfloat16* w1pack = (__hip_bfloat16*)(ws + OFF_W1P);
    float4* wlp = (float4*)(ws + OFF_WLP);
    float* bsum = (float*)(ws + OFF_BS);
    __hip_bfloat16* Sb = (__hip_bfloat16*)(ws + OFF_SB);
    __hip_bfloat16* Gt = (__hip_bfloat16*)(ws + OFF_GT);
    float* y1e = (float*)(ws + OFF_Y1);

    in_conv_kernel<<<dim3(T_IN / 256, BATCH), 256, 0, stream>>>(x, w_in, b_in, hA);
    pack_kernel<<<dim3(512 * 1600 / 256), 256, 0, stream>>>(
        w_skip, b_skip, w_post1, w_sig, w_tanh, Apack, w1pack, wlp, bsum);

    int L = T_IN;
    float* hin = hA;
    float* hout = hB;
    for (int i = 0; i < N_LAYERS; ++i) {
        int d = 1 << (i % 10);
        int Lout = L - d;
        dim3 grid((Lout + 63) / 64, BATCH);
        layer_kernel<<<grid, 256, 0, stream>>>(hin, hout, Gt,
            wlp, w_res, b_sig, b_tanh, b_res, i, d, L, Lout, Lout - OUT_LEN);
        float* tmp = hin; hin = hout; hout = tmp;
        L = Lout;
    }

    // skip GEMM: Sb[n][512] = bf16(elu(Apack(512x1600) * Gt^T + bsum))
    mfma_gemm_kernel<0><<<dim3((NCOL + 127) / 128, 4), 256, 0, stream>>>(
        Apack, 1600, Gt, 1600, bsum, (void*)Sb, 1600);
    // post1: y1e[512][NCOL] = elu(w1pack(512x512) * Sb^T + b_post1)
    mfma_gemm_kernel<1><<<dim3((NCOL + 127) / 128, 4), 256, 0, stream>>>(
        w1pack, 512, Sb, 512, b_post1, (void*)y1e, 512);
    post2_kernel<<<dim3((NCOL + 255) / 256), 256, 0, stream>>>(y1e, w_post2, b_post2, out, NCOL);
}

// Round 4
// 758.410 us; speedup vs baseline: 2.6435x; 1.7569x over previous
//
#include <hip/hip_runtime.h>
#include <hip/hip_bf16.h>

#define N_LAYERS 50
#define N_RES 32
#define N_SKIP 512
#define N_FEAT 8
#define BATCH 8
#define T_IN 8192
#define OUT_LEN 3077
#define NCOL (BATCH * OUT_LEN)   // 24616

typedef __bf16 bf16x8 __attribute__((ext_vector_type(8)));
typedef float  f32x4  __attribute__((ext_vector_type(4)));

// ---------------- workspace layout (bytes, all 256-aligned) ----------------
#define OFF_HA   ((size_t)0)
#define SZ_H     ((size_t)BATCH * T_IN * 32 * 4)            // 8,388,608  h fp32 [b][t][32]
#define OFF_HB   (OFF_HA + SZ_H)
#define OFF_WG   (OFF_HB + SZ_H)                            // wgpack bf16 [50][64][64]
#define SZ_WG    ((size_t)50 * 64 * 64 * 2)
#define OFF_WR   (OFF_WG + SZ_WG)                           // wrpack bf16 [50][32][32]
#define SZ_WR    ((size_t)50 * 32 * 32 * 2)
#define OFF_BG   (OFF_WR + SZ_WR)                           // bgate f32 [50][64]
#define SZ_BG    ((size_t)50 * 64 * 4)
#define OFF_AP   (OFF_BG + SZ_BG)                           // Apack bf16 [512][1600]
#define SZ_AP    ((size_t)512 * 1600 * 2)
#define OFF_W1P  (OFF_AP + SZ_AP)                           // w1pack bf16 [512][512]
#define SZ_W1P   ((size_t)512 * 512 * 2)
#define OFF_BS   (OFF_W1P + SZ_W1P)                         // bsum[512] f32
#define SZ_BS    ((size_t)2048)
#define OFF_SB   (OFF_BS + SZ_BS)                           // Sb bf16 [NCOL][512]  (elu applied)
#define SZ_SB    ((size_t)NCOL * 512 * 2)
#define OFF_GT   (OFF_SB + SZ_SB)                           // Gt bf16 [NCOL][1600]
#define SZ_GT    ((size_t)NCOL * 1600 * 2)
#define OFF_Y1   OFF_GT                                     // y1b bf16 [512][NCOL] aliases Gt

__device__ __forceinline__ float eluf(float v) {
    return v > 0.0f ? v : (__expf(v) - 1.0f);
}
__device__ __forceinline__ unsigned short f2bf_bits(float f) {
    __hip_bfloat16 h = __float2bfloat16(f);
    return *(unsigned short*)&h;
}
__device__ __forceinline__ void gl_lds16(const void* g, void* l) {
    __builtin_amdgcn_global_load_lds(
        (const __attribute__((address_space(1))) void*)g,
        (__attribute__((address_space(3))) void*)l, 16, 0, 0);
}

// ---------------- input 1x1 conv: h0 [b][t][32] ----------------
__global__ __launch_bounds__(256) void in_conv_kernel(
    const float* __restrict__ x, const float* __restrict__ w_in,
    const float* __restrict__ b_in, float* __restrict__ h0)
{
    int tid = threadIdx.x;
    int t = blockIdx.x * 32 + (tid >> 3);
    int grp = tid & 7;
    int b = blockIdx.y;
    const float* xp = x + ((size_t)b * T_IN + t) * 8;
    float4 v0 = *(const float4*)xp;
    float4 v1 = *(const float4*)(xp + 4);
    float xv[8] = {v0.x, v0.y, v0.z, v0.w, v1.x, v1.y, v1.z, v1.w};
    float4 o;
    float oo[4];
#pragma unroll
    for (int e = 0; e < 4; ++e) {
        int oc = grp * 4 + e;
        float acc = b_in[oc];
#pragma unroll
        for (int f = 0; f < 8; ++f) acc += w_in[oc * 8 + f] * xv[f];
        oo[e] = acc;
    }
    o.x = oo[0]; o.y = oo[1]; o.z = oo[2]; o.w = oo[3];
    *(float4*)(h0 + ((size_t)b * T_IN + t) * 32 + grp * 4) = o;
}

// ---------------- pack weights ----------------
__global__ __launch_bounds__(256) void pack_kernel(
    const float* __restrict__ w_skip, const float* __restrict__ b_skip,
    const float* __restrict__ w_post1,
    const float* __restrict__ w_sig, const float* __restrict__ w_tanh,
    const float* __restrict__ w_res,
    const float* __restrict__ b_sig, const float* __restrict__ b_tanh,
    __hip_bfloat16* __restrict__ Apack, __hip_bfloat16* __restrict__ w1pack,
    __hip_bfloat16* __restrict__ wgpack, __hip_bfloat16* __restrict__ wrpack,
    float* __restrict__ bgate, float* __restrict__ bsum)
{
    int tid = blockIdx.x * 256 + threadIdx.x;    // 0 .. 819199
    {   // Apack[m][i*32+c] = bf16(w_skip[i][m][c])
        int m = tid / 1600;
        int r = tid - m * 1600;
        int i = r >> 5, c = r & 31;
        Apack[tid] = __float2bfloat16(w_skip[((size_t)i * 512 + m) * 32 + c]);
    }
    if (tid < 512 * 512) w1pack[tid] = __float2bfloat16(w_post1[tid]);
    if (tid < 50 * 64 * 64) {     // wgpack[l][row=2c+f][k=tap*32+ci]
        int l = tid >> 12;
        int rem = tid & 4095;
        int row = rem >> 6, k = rem & 63;
        int c = row >> 1, f = row & 1;
        int tap = k >> 5, ci = k & 31;
        const float* src = f ? w_tanh : w_sig;
        wgpack[tid] = __float2bfloat16(src[(((size_t)l * 32 + c) * 32 + ci) * 2 + tap]);
    }
    if (tid < 50 * 1024) wrpack[tid] = __float2bfloat16(w_res[tid]);
    if (tid < 50 * 64) {
        int l = tid >> 6, row = tid & 63;
        bgate[tid] = (row & 1) ? b_tanh[l * 32 + (row >> 1)] : b_sig[l * 32 + (row >> 1)];
    }
    if (tid < 512) {
        float s = 0.0f;
        for (int l = 0; l < N_LAYERS; ++l) s += b_skip[l * 512 + tid];
        bsum[tid] = s;
    }
}

// ---------------- one dilated gated-conv layer, MFMA, hi/lo split X ----------------
// BN=128 cols/block, 4 waves x 32 cols. h layout [b][t][32] fp32.
// X staged as bf16 hi + bf16 lo (hi+lo ~ fp32): gate acc = Wg*X_hi + Wg*X_lo.
__global__ __launch_bounds__(256) void layer_kernel(
    const float* __restrict__ h_in, float* __restrict__ h_out,
    __hip_bfloat16* __restrict__ Gt,
    const __hip_bfloat16* __restrict__ wg, const __hip_bfloat16* __restrict__ wr,
    const float* __restrict__ bg, const float* __restrict__ br,
    int layer, int d, int Lin, int Lout, int win_start)
{
    __shared__ __align__(16) char xs_hi[128 * 128];  // bf16 [col][k=64], XOR-swizzled 16B chunks
    __shared__ __align__(16) char xs_lo[128 * 128];
    __shared__ __align__(16) char gs[128 * 80];      // bf16 [col][ch=32], row stride 80 B
    const int tid = threadIdx.x;
    const int lane = tid & 63;
    const int wave = tid >> 6;
    const int q = lane >> 4, r = lane & 15;
    const int b = blockIdx.y;
    const int t0 = blockIdx.x * 128;
    const float* hb = h_in + (size_t)b * Lin * 32;

    // ---- stage X tiles (fp32 -> bf16 hi/lo -> LDS) ----
#pragma unroll
    for (int it = 0; it < 4; ++it) {
        int lin = it * 256 + tid;
        int col = lin >> 3, hc = lin & 7;
        int tap = hc >> 2, ch0 = (hc & 3) * 8;
        int t = t0 + col; t = t < Lout ? t : Lout - 1;
        const float* src = hb + (size_t)(t + tap * d) * 32 + ch0;
        float4 v0 = *(const float4*)src;
        float4 v1 = *(const float4*)(src + 4);
        float vv[8] = {v0.x, v0.y, v0.z, v0.w, v1.x, v1.y, v1.z, v1.w};
        union { bf16x8 v; unsigned short u[8]; } hi, lo;
#pragma unroll
        for (int e = 0; e < 8; ++e) {
            unsigned short hbits = f2bf_bits(vv[e]);
            hi.u[e] = hbits;
            float hf = __uint_as_float((unsigned)hbits << 16);
            lo.u[e] = f2bf_bits(vv[e] - hf);
        }
        int off = col * 128 + ((hc ^ (col & 7)) * 16);
        *(bf16x8*)(xs_hi + off) = hi.v;
        *(bf16x8*)(xs_lo + off) = lo.v;
    }

    // ---- weight fragments from global (L2-hot) ----
    bf16x8 af[4][2];
#pragma unroll
    for (int i = 0; i < 4; ++i)
#pragma unroll
        for (int ks = 0; ks < 2; ++ks)
            af[i][ks] = *(const bf16x8*)(wg + ((16 * i + r) * 64 + ks * 32 + q * 8));
    bf16x8 ar[2];
#pragma unroll
    for (int i = 0; i < 2; ++i)
        ar[i] = *(const bf16x8*)(wr + ((16 * i + r) * 32 + q * 8));

    __syncthreads();

    // ---- gate GEMM (hi + lo) ----
    const int c0 = wave * 32;
    f32x4 acc[4][2] = {};
#pragma unroll
    for (int jj = 0; jj < 2; ++jj) {
        int col = c0 + 16 * jj + r;
#pragma unroll
        for (int ks = 0; ks < 2; ++ks) {
            int off = col * 128 + (((ks * 4 + q) ^ (col & 7)) * 16);
            bf16x8 bhi = *(const bf16x8*)(xs_hi + off);
            bf16x8 blo = *(const bf16x8*)(xs_lo + off);
#pragma unroll
            for (int i = 0; i < 4; ++i) {
                acc[i][jj] = __builtin_amdgcn_mfma_f32_16x16x32_bf16(af[i][ks], bhi, acc[i][jj], 0, 0, 0);
                acc[i][jj] = __builtin_amdgcn_mfma_f32_16x16x32_bf16(af[i][ks], blo, acc[i][jj], 0, 0, 0);
            }
        }
    }

    // ---- gates -> gs ----
#pragma unroll
    for (int i = 0; i < 4; ++i) {
        float4 bb = *(const float4*)(bg + 16 * i + 4 * q);
#pragma unroll
        for (int jj = 0; jj < 2; ++jj) {
            int col = c0 + 16 * jj + r;
            float ps0 = acc[i][jj][0] + bb.x;
            float pt0 = acc[i][jj][1] + bb.y;
            float ps1 = acc[i][jj][2] + bb.z;
            float pt1 = acc[i][jj][3] + bb.w;
            float g0 = (1.0f / (1.0f + __expf(-ps0))) * (1.0f - 2.0f / (__expf(2.0f * pt0) + 1.0f));
            float g1 = (1.0f / (1.0f + __expf(-ps1))) * (1.0f - 2.0f / (__expf(2.0f * pt1) + 1.0f));
            unsigned int w = f2bf_bits(g0) | ((unsigned)f2bf_bits(g1) << 16);
            *(unsigned int*)(gs + col * 80 + (16 * i + 4 * q)) = w;
        }
    }
    __syncthreads();

    // ---- Gt write (coalesced 16B per lane) ----
#pragma unroll
    for (int it = 0; it < 2; ++it) {
        int lin = it * 256 + tid;
        int col = lin >> 2, qq = lin & 3;
        int t = t0 + col;
        if (t >= win_start && t < Lout) {
            uint4 v = *(const uint4*)(gs + col * 80 + qq * 16);
            size_t n = (size_t)b * OUT_LEN + (t - win_start);
            *(uint4*)(Gt + n * 1600 + layer * 32 + qq * 8) = v;
        }
    }

    // ---- res GEMM + fp32 residual ----
    f32x4 racc[2][2] = {};
#pragma unroll
    for (int jj = 0; jj < 2; ++jj) {
        int col = c0 + 16 * jj + r;
        bf16x8 gb = *(const bf16x8*)(gs + col * 80 + q * 16);
#pragma unroll
        for (int i = 0; i < 2; ++i)
            racc[i][jj] = __builtin_amdgcn_mfma_f32_16x16x32_bf16(ar[i], gb, racc[i][jj], 0, 0, 0);
    }
#pragma unroll
    for (int i = 0; i < 2; ++i) {
        int ch = 16 * i + 4 * q;
        float4 bb = *(const float4*)(br + ch);
#pragma unroll
        for (int jj = 0; jj < 2; ++jj) {
            int t = t0 + c0 + 16 * jj + r;
            if (t < Lout) {
                float4 rv = *(const float4*)(hb + (size_t)(t + d) * 32 + ch);
                float4 o;
                o.x = racc[i][jj][0] + bb.x + rv.x;
                o.y = racc[i][jj][1] + bb.y + rv.y;
                o.z = racc[i][jj][2] + bb.z + rv.z;
                o.w = racc[i][jj][3] + bb.w + rv.w;
                *(float4*)(h_out + ((size_t)b * Lout + t) * 32 + ch) = o;
            }
        }
    }
}

// ---------------- MFMA GEMM: C[m][n] = sum_k A[m][k]*B[n][k] + bias[m] ----------------
// MODE 0: skip  -> Sb bf16 [n][512] = bf16(elu(acc+bias))
// MODE 1: post1 -> y1b bf16 [m][NCOL] = bf16(elu(acc+bias))
template <int MODE>
__global__ __launch_bounds__(256) void mfma_gemm_kernel(
    const __hip_bfloat16* __restrict__ A, int lda,
    const __hip_bfloat16* __restrict__ B, int ldb,
    const float* __restrict__ bias, void* __restrict__ Cout, int K)
{
    __shared__ __align__(16) char As[128 * 128];
    __shared__ __align__(16) char Bs[128 * 128];
    int tid = threadIdx.x;
    int lane = tid & 63, wave = tid >> 6;
    int m0 = blockIdx.x * 128, n0 = blockIdx.y * 128;
    int wm = (wave & 1) * 64, wn = (wave >> 1) * 64;
    int q = lane >> 4, r = lane & 15;

    f32x4 acc[4][4] = {};

    for (int k0 = 0; k0 < K; k0 += 64) {
        __syncthreads();
#pragma unroll
        for (int i = 0; i < 4; ++i) {
            int li = i * 256 + tid;
            int row = li >> 3, ch = li & 7;
            int cs = (ch ^ (row & 7)) * 8;
            gl_lds16(A + (size_t)(m0 + row) * lda + k0 + cs, As + li * 16);
            int gn = n0 + row; if (gn > NCOL - 1) gn = NCOL - 1;
            gl_lds16(B + (size_t)gn * ldb + k0 + cs, Bs + li * 16);
        }
        __syncthreads();
#pragma unroll
        for (int ks = 0; ks < 2; ++ks) {
            bf16x8 af[4], bfr[4];
#pragma unroll
            for (int s = 0; s < 4; ++s) {
                int m = wm + s * 16 + r;
                int cg = ks * 4 + q;
                af[s]  = *(const bf16x8*)(As + m * 128 + ((cg ^ (m & 7)) * 16));
                int n = wn + s * 16 + r;
                bfr[s] = *(const bf16x8*)(Bs + n * 128 + ((cg ^ (n & 7)) * 16));
            }
#pragma unroll
            for (int i = 0; i < 4; ++i)
#pragma unroll
                for (int j = 0; j < 4; ++j)
                    acc[i][j] = __builtin_amdgcn_mfma_f32_16x16x32_bf16(
                        af[i], bfr[j], acc[i][j], 0, 0, 0);
        }
    }

    if (MODE == 0) {
        __hip_bfloat16* Sb = (__hip_bfloat16*)Cout;
#pragma unroll
        for (int j = 0; j < 4; ++j) {
            int n = n0 + wn + j * 16 + r;
            if (n >= NCOL) continue;
#pragma unroll
            for (int i = 0; i < 4; ++i) {
                int mb = m0 + wm + i * 16 + q * 4;
                float4 bs = *(const float4*)(bias + mb);
                ushort4 u;
                u.x = f2bf_bits(eluf(acc[i][j][0] + bs.x));
                u.y = f2bf_bits(eluf(acc[i][j][1] + bs.y));
                u.z = f2bf_bits(eluf(acc[i][j][2] + bs.z));
                u.w = f2bf_bits(eluf(acc[i][j][3] + bs.w));
                *(ushort4*)(Sb + (size_t)n * 512 + mb) = u;
            }
        }
    } else {
        __hip_bfloat16* y1b = (__hip_bfloat16*)Cout;
#pragma unroll
        for (int i = 0; i < 4; ++i) {
            int mb = m0 + wm + i * 16 + q * 4;
            float4 bs = *(const float4*)(bias + mb);
#pragma unroll
            for (int rr = 0; rr < 4; ++rr) {
                float bb = (rr == 0) ? bs.x : (rr == 1) ? bs.y : (rr == 2) ? bs.z : bs.w;
#pragma unroll
                for (int j = 0; j < 4; ++j) {
                    int n = n0 + wn + j * 16 + r;
                    if (n < NCOL)
                        y1b[(size_t)(mb + rr) * NCOL + n] =
                            __float2bfloat16(eluf(acc[i][j][rr] + bb));
                }
            }
        }
    }
}

// ---------------- post2: out[n] = b2 + sum_k w2[k]*y1b[k][n] ----------------
__global__ __launch_bounds__(256) void post2_kernel(
    const __hip_bfloat16* __restrict__ y1b, const float* __restrict__ w2,
    const float* __restrict__ b2, float* __restrict__ out, int N)
{
    int n = blockIdx.x * 256 + threadIdx.x;
    if (n >= N) return;
    float acc = b2[0];
    for (int k = 0; k < N_SKIP; ++k)
        acc += w2[k] * __bfloat162float(y1b[(size_t)k * N + n]);
    out[n] = acc;
}

extern "C" void kernel_launch(void* const* d_in, const int* in_sizes, int n_in,
                              void* d_out, int out_size, void* d_ws, size_t ws_size,
                              hipStream_t stream)
{
    const float* x      = (const float*)d_in[0];
    const float* w_in   = (const float*)d_in[1];
    const float* b_in   = (const float*)d_in[2];
    const float* w_sig  = (const float*)d_in[3];
    const float* b_sig  = (const float*)d_in[4];
    const float* w_tanh = (const float*)d_in[5];
    const float* b_tanh = (const float*)d_in[6];
    const float* w_skip = (const float*)d_in[7];
    const float* b_skip = (const float*)d_in[8];
    const float* w_res  = (const float*)d_in[9];
    const float* b_res  = (const float*)d_in[10];
    const float* w_post1 = (const float*)d_in[11];
    const float* b_post1 = (const float*)d_in[12];
    const float* w_post2 = (const float*)d_in[13];
    const float* b_post2 = (const float*)d_in[14];
    float* out = (float*)d_out;

    char* ws = (char*)d_ws;
    float* hA = (float*)(ws + OFF_HA);
    float* hB = (float*)(ws + OFF_HB);
    __hip_bfloat16* wgpack = (__hip_bfloat16*)(ws + OFF_WG);
    __hip_bfloat16* wrpack = (__hip_bfloat16*)(ws + OFF_WR);
    float* bgate = (float*)(ws + OFF_BG);
    __hip_bfloat16* Apack  = (__hip_bfloat16*)(ws + OFF_AP);
    __hip_bfloat16* w1pack = (__hip_bfloat16*)(ws + OFF_W1P);
    float* bsum = (float*)(ws + OFF_BS);
    __hip_bfloat16* Sb = (__hip_bfloat16*)(ws + OFF_SB);
    __hip_bfloat16* Gt = (__hip_bfloat16*)(ws + OFF_GT);
    __hip_bfloat16* y1b = (__hip_bfloat16*)(ws + OFF_Y1);

    in_conv_kernel<<<dim3(T_IN / 32, BATCH), 256, 0, stream>>>(x, w_in, b_in, hA);
    pack_kernel<<<dim3(512 * 1600 / 256), 256, 0, stream>>>(
        w_skip, b_skip, w_post1, w_sig, w_tanh, w_res, b_sig, b_tanh,
        Apack, w1pack, wgpack, wrpack, bgate, bsum);

    int L = T_IN;
    float* hin = hA;
    float* hout = hB;
    for (int i = 0; i < N_LAYERS; ++i) {
        int d = 1 << (i % 10);
        int Lout = L - d;
        dim3 grid((Lout + 127) / 128, BATCH);
        layer_kernel<<<grid, 256, 0, stream>>>(hin, hout, Gt,
            wgpack + (size_t)i * 4096, wrpack + (size_t)i * 1024,
            bgate + i * 64, b_res + i * 32,
            i, d, L, Lout, Lout - OUT_LEN);
        float* tmp = hin; hin = hout; hout = tmp;
        L = Lout;
    }

    // skip GEMM: Sb[n][512] = bf16(elu(Apack(512x1600) * Gt^T + bsum))
    mfma_gemm_kernel<0><<<dim3(4, (NCOL + 127) / 128), 256, 0, stream>>>(
        Apack, 1600, Gt, 1600, bsum, (void*)Sb, 1600);
    // post1: y1b[512][NCOL] = bf16(elu(w1pack(512x512) * Sb^T + b_post1))
    mfma_gemm_kernel<1><<<dim3(4, (NCOL + 127) / 128), 256, 0, stream>>>(
        w1pack, 512, Sb, 512, b_post1, (void*)y1b, 512);
    post2_kernel<<<dim3((NCOL + 255) / 256), 256, 0, stream>>>(y1b, w_post2, b_post2, out, NCOL);
}